// Round 1
// baseline (259.690 us; speedup 1.0000x reference)
//
#include <hip/hip_runtime.h>
#include <hip/hip_bf16.h>
#include <hip/hip_fp16.h>

#define N_NODES 50000
#define N_EDGES 1600000
#define IN_CH 256
#define NEG_SLOPE 0.2f
#define EPS_F 1e-16f
#define CNT_PAD 16      // one 64B line per counter (agg kernels read cnt[n*16])
#define CAP 128         // bucket capacity per node (Poisson(32): P(>=128) ~ 1e-37)
#define NBK 196         // coarse buckets: dst>>8, 50000/256 -> 0..195
#define CAPB 10240      // coarse bucket capacity (mean 8163, +23 sigma)
#define PCHUNK 3125     // edges per k_part block (512 * 3125 = 1.6M)
#define KTILE 64                 // 17.4KB xs + 32KB w1s -> 3 blocks/CU
#define XS_PITCH (KTILE + 4)

__device__ __forceinline__ float lrelu(float x) {
    return x > 0.f ? x : NEG_SLOPE * x;
}

__device__ __forceinline__ float2 h2f(unsigned int w) {
    __half2 h;
    *reinterpret_cast<unsigned int*>(&h) = w;
    return __half22float2(h);
}

__device__ __forceinline__ unsigned int f2h2(float a, float b) {
    __half2 h = __floats2half2_rn(a, b);
    return *reinterpret_cast<unsigned int*>(&h);
}

// -------- Kernel 0a: detect edge_index storage; zero gcnt --------
__global__ __launch_bounds__(256) void k0_detect(const int* __restrict__ ei,
                                                 int* __restrict__ flag,
                                                 int* __restrict__ gcnt)
{
    __shared__ int nz;
    const int t = threadIdx.x;
    if (t == 0) nz = 0;
    if (t < 256) gcnt[t] = 0;
    __syncthreads();
    if (t & 1) { if (ei[t] != 0) atomicAdd(&nz, 1); }
    __syncthreads();
    if (t == 0) flag[0] = (nz == 0) ? 1 : 0;   // 1 => int64 layout
}

__device__ __forceinline__ int ld_src(const int* ei, int f, int e) {
    return f ? ei[2 * (size_t)e] : ei[e];
}
__device__ __forceinline__ int ld_dst(const int* ei, int f, int e) {
    return f ? ei[2 * (size_t)N_EDGES + 2 * (size_t)e]
             : ei[(size_t)N_EDGES + e];
}

// -------- Build pass 1: coarse partition by dst>>8 (LDS hist + cursors) --------
__global__ __launch_bounds__(1024) void k_part(const int* __restrict__ ei,
                                               const int* __restrict__ flag,
                                               int* __restrict__ gcnt,
                                               int2* __restrict__ bseg)
{
    __shared__ int hist[NBK];
    __shared__ int cur[NBK];
    const int t = threadIdx.x;
    for (int j = t; j < NBK; j += 1024) hist[j] = 0;
    __syncthreads();
    const int f = flag[0];
    const int e0 = blockIdx.x * PCHUNK;
    const int e1 = min(e0 + PCHUNK, N_EDGES);
    for (int e = e0 + t; e < e1; e += 1024)
        atomicAdd(&hist[ld_dst(ei, f, e) >> 8], 1);
    __syncthreads();
    for (int j = t; j < NBK; j += 1024)
        cur[j] = j * CAPB + atomicAdd(&gcnt[j], hist[j]);
    __syncthreads();
    for (int e = e0 + t; e < e1; e += 1024) {
        const int s = ld_src(ei, f, e);
        const int d = ld_dst(ei, f, e);
        const int bk = d >> 8;
        const int pos = atomicAdd(&cur[bk], 1);
        if (pos - bk * CAPB < CAPB) bseg[pos] = make_int2(s, d);
    }
}

// -------- Build pass 2: per-bucket fine scatter into fixed-stride CSR --------
__global__ __launch_bounds__(1024) void k_sub(const int* __restrict__ gcnt,
                                              const int2* __restrict__ bseg,
                                              int* __restrict__ cnt,
                                              int* __restrict__ csr_src)
{
    __shared__ int cur[256];
    const int b = blockIdx.x;
    const int t = threadIdx.x;
    if (t < 256) cur[t] = 0;
    __syncthreads();
    const int count = min(gcnt[b], CAPB);
    const int2* seg = bseg + (size_t)b * CAPB;
    for (int i = t; i < count; i += 1024) {
        const int2 e = seg[i];
        const int slot = atomicAdd(&cur[e.y & 255], 1);
        if (slot < CAP) csr_src[((size_t)e.y << 7) + slot] = e.x;
    }
    __syncthreads();
    if (t < 256) {
        const int n = b * 256 + t;
        if (n < N_NODES) cnt[(size_t)n * CNT_PAD] = min(cur[t], CAP);
    }
}

// ---------------- Kernel 1: h1 = x @ W1 (fp16 out) ; a_src1/a_dst1 fused ----------------
// Register-blocked 2 rows x 4 cols; KTILE=64 for 3 blocks/CU occupancy.
__global__ __launch_bounds__(256) void k1_gemm1(
    const float* __restrict__ x, const float* __restrict__ W1,
    const float* __restrict__ att_src1, const float* __restrict__ att_dst1,
    __half* __restrict__ h1, float* __restrict__ a_src1, float* __restrict__ a_dst1)
{
    __shared__ float w1s[IN_CH * 32];        // full K, [k][col]  (32 KB)
    __shared__ float xs[64 * XS_PITCH];      // K-tile of 64      (17.4 KB)
    __shared__ float attss[32], attds[32];
    const int t = threadIdx.x;
    for (int i = t; i < IN_CH * 32; i += 256) w1s[i] = W1[i];
    if (t < 32) { attss[t] = att_src1[t]; attds[t] = att_dst1[t]; }
    const int row0 = blockIdx.x * 64;
    const int colq = t & 7, c4 = colq * 4;
    const int rp = t >> 3;
    const int r0 = rp * 2, r1 = r0 + 1;
    float4 a0 = make_float4(0.f, 0.f, 0.f, 0.f);
    float4 a1 = make_float4(0.f, 0.f, 0.f, 0.f);
    for (int kb = 0; kb < IN_CH; kb += KTILE) {
        __syncthreads();
        #pragma unroll
        for (int i = 0; i < 4; ++i) {        // 64 rows x 16 float4
            const int idx = t + 256 * i;
            const int r = idx >> 4, p = idx & 15;
            const int row = row0 + r;
            float4 vv = make_float4(0.f, 0.f, 0.f, 0.f);
            if (row < N_NODES)
                vv = *(const float4*)(x + (size_t)row * IN_CH + kb + p * 4);
            *(float4*)(&xs[r * XS_PITCH + p * 4]) = vv;
        }
        __syncthreads();
        #pragma unroll 8
        for (int kt = 0; kt < KTILE; ++kt) {
            const float xv0 = xs[r0 * XS_PITCH + kt];
            const float xv1 = xs[r1 * XS_PITCH + kt];
            const float4 wv = *(const float4*)(&w1s[(kb + kt) * 32 + c4]);
            a0.x += xv0 * wv.x; a0.y += xv0 * wv.y;
            a0.z += xv0 * wv.z; a0.w += xv0 * wv.w;
            a1.x += xv1 * wv.x; a1.y += xv1 * wv.y;
            a1.z += xv1 * wv.z; a1.w += xv1 * wv.w;
        }
    }
    const int row_a = row0 + r0, row_b = row0 + r1;
    if (row_a < N_NODES) {
        uint2 p; p.x = f2h2(a0.x, a0.y); p.y = f2h2(a0.z, a0.w);
        *(uint2*)(h1 + (size_t)row_a * 32 + c4) = p;
    }
    if (row_b < N_NODES) {
        uint2 p; p.x = f2h2(a1.x, a1.y); p.y = f2h2(a1.z, a1.w);
        *(uint2*)(h1 + (size_t)row_b * 32 + c4) = p;
    }
    float sa0 = a0.x * attss[c4] + a0.y * attss[c4 + 1]
              + a0.z * attss[c4 + 2] + a0.w * attss[c4 + 3];
    float sd0 = a0.x * attds[c4] + a0.y * attds[c4 + 1]
              + a0.z * attds[c4 + 2] + a0.w * attds[c4 + 3];
    float sa1 = a1.x * attss[c4] + a1.y * attss[c4 + 1]
              + a1.z * attss[c4 + 2] + a1.w * attss[c4 + 3];
    float sd1 = a1.x * attds[c4] + a1.y * attds[c4 + 1]
              + a1.z * attds[c4 + 2] + a1.w * attds[c4 + 3];
    sa0 += __shfl_xor(sa0, 1); sa0 += __shfl_xor(sa0, 2);
    sd0 += __shfl_xor(sd0, 1); sd0 += __shfl_xor(sd0, 2);
    sa1 += __shfl_xor(sa1, 1); sa1 += __shfl_xor(sa1, 2);
    sd1 += __shfl_xor(sd1, 1); sd1 += __shfl_xor(sd1, 2);
    const int head = colq >> 2;
    if ((colq & 3) == 0) {
        if (row_a < N_NODES) {
            a_src1[row_a * 2 + head] = sa0;
            a_dst1[row_a * 2 + head] = sd0;
        }
        if (row_b < N_NODES) {
            a_src1[row_b * 2 + head] = sa1;
            a_dst1[row_b * 2 + head] = sd1;
        }
    }
}

// -------- Layer-1 aggregation: half2-packed gathers, 4 edge-slots/wave --------
// Lane map: chp = lane&15 -> channels {2chp, 2chp+1}; slot = lane>>4 -> 4 edges in flight.
// Per edge the h1 gather is 16 lanes x 4B = one 64B line (same lines as before,
// half the VMEM instructions).
__global__ __launch_bounds__(256) void k_agg1(
    const int* __restrict__ cnt, const int* __restrict__ csr_src,
    const float* __restrict__ a_src1, const float* __restrict__ a_dst1,
    const __half* __restrict__ h1, float* __restrict__ out1)
{
    const int wid = (blockIdx.x * 256 + threadIdx.x) >> 6;
    const int lane = threadIdx.x & 63;
    if (wid >= N_NODES) return;
    const int len = min(cnt[(size_t)wid * CNT_PAD], CAP);
    const int beg = wid << 7, end = beg + len;
    const float2 ad = *(const float2*)(a_dst1 + 2 * (size_t)wid);
    const int slot = lane >> 4, chp = lane & 15;
    const int head = chp >> 3;
    const float adh = head ? ad.y : ad.x;
    const int rep = ((chp & 7) == 0);
    const unsigned int* __restrict__ h1u = (const unsigned int*)h1;
    float accx = 0.f, accy = 0.f, sw = 0.f;
    int i = beg + slot;
    for (; i + 28 < end; i += 32) {          // 32 edges / wave-iter
        int s[8]; float a[8]; unsigned int hw[8]; float w[8];
        #pragma unroll
        for (int j = 0; j < 8; ++j) s[j] = csr_src[i + 4 * j];
        #pragma unroll
        for (int j = 0; j < 8; ++j) a[j] = a_src1[2 * (size_t)s[j] + head];
        #pragma unroll
        for (int j = 0; j < 8; ++j) hw[j] = h1u[(size_t)s[j] * 16 + chp];
        #pragma unroll
        for (int j = 0; j < 8; ++j) w[j] = __expf(lrelu(a[j] + adh));
        float wsum = 0.f;
        #pragma unroll
        for (int j = 0; j < 8; ++j) {
            const float2 hf = h2f(hw[j]);
            wsum += w[j];
            accx += w[j] * hf.x; accy += w[j] * hf.y;
        }
        if (rep) sw += wsum;
    }
    for (; i + 12 < end; i += 16) {          // mid tier: 16 edges / wave-iter
        int s[4]; float a[4]; unsigned int hw[4]; float w[4];
        #pragma unroll
        for (int j = 0; j < 4; ++j) s[j] = csr_src[i + 4 * j];
        #pragma unroll
        for (int j = 0; j < 4; ++j) a[j] = a_src1[2 * (size_t)s[j] + head];
        #pragma unroll
        for (int j = 0; j < 4; ++j) hw[j] = h1u[(size_t)s[j] * 16 + chp];
        #pragma unroll
        for (int j = 0; j < 4; ++j) w[j] = __expf(lrelu(a[j] + adh));
        float wsum = 0.f;
        #pragma unroll
        for (int j = 0; j < 4; ++j) {
            const float2 hf = h2f(hw[j]);
            wsum += w[j];
            accx += w[j] * hf.x; accy += w[j] * hf.y;
        }
        if (rep) sw += wsum;
    }
    for (; i < end; i += 4) {
        const int s = csr_src[i];
        const float w = __expf(lrelu(a_src1[2 * (size_t)s + head] + adh));
        if (rep) sw += w;
        const float2 hf = h2f(h1u[(size_t)s * 16 + chp]);
        accx += w * hf.x; accy += w * hf.y;
    }
    // reduce across the 4 slots (lanes differ in bits 4,5)
    sw += __shfl_xor(sw, 16); sw += __shfl_xor(sw, 32);
    const float swh = __shfl(sw, head << 3);
    accx += __shfl_xor(accx, 16); accx += __shfl_xor(accx, 32);
    accy += __shfl_xor(accy, 16); accy += __shfl_xor(accy, 32);
    const float inv = 1.f / (swh + EPS_F);
    if (lane < 16) {
        float2 o; o.x = accx * inv; o.y = accy * inv;
        *(float2*)(out1 + (size_t)wid * 32 + 2 * chp) = o;
    }
}

// ---------------- Kernel 4: h2 = elu(out1+b1) @ W2 (fp16 out) ; a_src2/a_dst2 fused ----------------
__global__ __launch_bounds__(256) void k4_layer2(
    const float* __restrict__ out1, const float* __restrict__ b1,
    const float* __restrict__ W2, const float* __restrict__ att_src2,
    const float* __restrict__ att_dst2,
    __half* __restrict__ h2, float* __restrict__ a_src2, float* __restrict__ a_dst2)
{
    __shared__ float act[16][32];
    __shared__ float w2s[32 * 16];
    __shared__ float b1s[32], as2[16], ad2[16];
    const int t = threadIdx.x;
    for (int i = t; i < 512; i += 256) w2s[i] = W2[i];
    if (t < 32) b1s[t] = b1[t];
    if (t < 16) { as2[t] = att_src2[t]; ad2[t] = att_dst2[t]; }
    __syncthreads();
    const int node0 = blockIdx.x * 16;
    for (int i = t; i < 512; i += 256) {
        const int nl = i >> 5, k = i & 31;
        const int row = node0 + nl;
        float v = 0.f;
        if (row < N_NODES) {
            v = out1[(size_t)row * 32 + k] + b1s[k];
            v = v > 0.f ? v : expm1f(v);
        }
        act[nl][k] = v;
    }
    __syncthreads();
    const int nl = t >> 4, j = t & 15;
    const int row = node0 + nl;
    float acc = 0.f;
    #pragma unroll
    for (int k = 0; k < 32; ++k) acc += act[nl][k] * w2s[k * 16 + j];
    if (row < N_NODES) h2[(size_t)row * 16 + j] = __float2half(acc);
    float sa = acc * as2[j], sd = acc * ad2[j];
    #pragma unroll
    for (int m = 1; m < 16; m <<= 1) { sa += __shfl_xor(sa, m); sd += __shfl_xor(sd, m); }
    if (j == 0 && row < N_NODES) { a_src2[row] = sa; a_dst2[row] = sd; }
}

// -------- Layer-2 aggregation: half2-packed h2 gathers, 8 edge-slots/wave --------
// Lane map: chp = lane&7 -> channels {2chp, 2chp+1}; slot = lane>>3 -> 8 edges in flight.
// Per edge the h2 gather is 8 lanes x 4B = 32B (half the bytes of fp32, half the instrs).
__global__ __launch_bounds__(256) void k_agg2(
    const int* __restrict__ cnt, const int* __restrict__ csr_src,
    const float* __restrict__ a_src2, const float* __restrict__ a_dst2,
    const __half* __restrict__ h2, float* __restrict__ out2)
{
    const int wid = (blockIdx.x * 256 + threadIdx.x) >> 6;
    const int lane = threadIdx.x & 63;
    if (wid >= N_NODES) return;
    const int len = min(cnt[(size_t)wid * CNT_PAD], CAP);
    const int beg = wid << 7, end = beg + len;
    const float ad = a_dst2[wid];
    const int slot = lane >> 3, chp = lane & 7;
    const int rep = (chp == 0);
    const unsigned int* __restrict__ h2u = (const unsigned int*)h2;
    float accx = 0.f, accy = 0.f, sw = 0.f;
    int i = beg + slot;
    for (; i + 24 < end; i += 32) {          // 32 edges / wave-iter
        int s[4]; float a[4]; unsigned int hw[4]; float w[4];
        #pragma unroll
        for (int j = 0; j < 4; ++j) s[j] = csr_src[i + 8 * j];
        #pragma unroll
        for (int j = 0; j < 4; ++j) a[j] = a_src2[s[j]];
        #pragma unroll
        for (int j = 0; j < 4; ++j) hw[j] = h2u[(size_t)s[j] * 8 + chp];
        #pragma unroll
        for (int j = 0; j < 4; ++j) w[j] = __expf(lrelu(a[j] + ad));
        float wsum = 0.f;
        #pragma unroll
        for (int j = 0; j < 4; ++j) {
            const float2 hf = h2f(hw[j]);
            wsum += w[j];
            accx += w[j] * hf.x; accy += w[j] * hf.y;
        }
        if (rep) sw += wsum;
    }
    for (; i < end; i += 8) {
        const int s = csr_src[i];
        const float w = __expf(lrelu(a_src2[s] + ad));
        if (rep) sw += w;
        const float2 hf = h2f(h2u[(size_t)s * 8 + chp]);
        accx += w * hf.x; accy += w * hf.y;
    }
    // reduce across the 8 slots (lanes differ in bits 3,4,5)
    sw += __shfl_xor(sw, 8); sw += __shfl_xor(sw, 16); sw += __shfl_xor(sw, 32);
    const float swt = __shfl(sw, 0);
    accx += __shfl_xor(accx, 8); accx += __shfl_xor(accx, 16); accx += __shfl_xor(accx, 32);
    accy += __shfl_xor(accy, 8); accy += __shfl_xor(accy, 16); accy += __shfl_xor(accy, 32);
    const float inv = 1.f / (swt + EPS_F);
    if (lane < 8) {
        float2 o; o.x = accx * inv; o.y = accy * inv;
        *(float2*)(out2 + (size_t)wid * 16 + 2 * chp) = o;
    }
}

// -------- k_prep: hoist edge-MLP first layer to nodes (fp16 u/v) --------
__global__ __launch_bounds__(256) void k_prep(
    const float* __restrict__ out2, const float* __restrict__ b2,
    const float* __restrict__ Wm1, const float* __restrict__ bm1,
    __half* __restrict__ u, __half* __restrict__ v)
{
    __shared__ float wa[16 * 16], wb[16 * 16];
    __shared__ float act[16][17];
    __shared__ float b2s[16], bm1s[16];
    const int t = threadIdx.x;
    if (t < 256) {
        const int k = t >> 4, j = t & 15;
        wa[t] = Wm1[k * 16 + j];
        wb[t] = Wm1[(16 + k) * 16 + j];
    }
    if (t < 16) { b2s[t] = b2[t]; bm1s[t] = bm1[t]; }
    __syncthreads();
    const int node0 = blockIdx.x * 16;
    const int nl = t >> 4, c = t & 15;
    const int row = node0 + nl;
    act[nl][c] = (row < N_NODES) ? out2[(size_t)row * 16 + c] + b2s[c] : 0.f;
    __syncthreads();
    float su = bm1s[c], sv = 0.f;
    #pragma unroll
    for (int k = 0; k < 16; ++k) {
        const float a = act[nl][k];
        su += a * wa[k * 16 + c];
        sv += a * wb[k * 16 + c];
    }
    if (row < N_NODES) {
        u[(size_t)row * 16 + c] = __float2half(su);
        v[(size_t)row * 16 + c] = __float2half(sv);
    }
}

// ---------------- Kernel 7 lite: per-edge tail of the MLP (fp16 gathers) ----------------
__global__ __launch_bounds__(256) void k7_lite(
    const int* __restrict__ ei, const int* __restrict__ flag,
    const __half* __restrict__ u, const __half* __restrict__ v,
    const float* __restrict__ Wm2, const float* __restrict__ bm2,
    float* __restrict__ out)
{
    __shared__ float wm2s[16];
    __shared__ float bm2s;
    const int t = threadIdx.x;
    if (t < 16) wm2s[t] = Wm2[t];
    if (t == 0) bm2s = bm2[0];
    __syncthreads();
    const int e = blockIdx.x * 256 + t;
    if (e >= N_EDGES) return;
    const int f = flag[0];
    const int s = ld_src(ei, f, e);
    const int d = ld_dst(ei, f, e);
    const uint4* up = (const uint4*)(u + (size_t)s * 16);
    const uint4* vp = (const uint4*)(v + (size_t)d * 16);
    const uint4 ua = up[0], ub = up[1];
    const uint4 va = vp[0], vb = vp[1];
    float fl = bm2s;
    unsigned int uw[8] = {ua.x, ua.y, ua.z, ua.w, ub.x, ub.y, ub.z, ub.w};
    unsigned int vw[8] = {va.x, va.y, va.z, va.w, vb.x, vb.y, vb.z, vb.w};
    #pragma unroll
    for (int i = 0; i < 8; ++i) {
        const float2 a = h2f(uw[i]);
        const float2 b = h2f(vw[i]);
        fl += fmaxf(a.x + b.x, 0.f) * wm2s[2 * i];
        fl += fmaxf(a.y + b.y, 0.f) * wm2s[2 * i + 1];
    }
    out[e] = fmaxf(fl, 0.f);
}

extern "C" void kernel_launch(void* const* d_in, const int* in_sizes, int n_in,
                              void* d_out, int out_size, void* d_ws, size_t ws_size,
                              hipStream_t stream)
{
    const float* x        = (const float*)d_in[0];
    const int*   ei       = (const int*)d_in[1];
    const float* W1       = (const float*)d_in[2];
    const float* att_src1 = (const float*)d_in[3];
    const float* att_dst1 = (const float*)d_in[4];
    const float* b1       = (const float*)d_in[5];
    const float* W2       = (const float*)d_in[6];
    const float* att_src2 = (const float*)d_in[7];
    const float* att_dst2 = (const float*)d_in[8];
    const float* b2       = (const float*)d_in[9];
    const float* Wm1      = (const float*)d_in[10];
    const float* bm1      = (const float*)d_in[11];
    const float* Wm2      = (const float*)d_in[12];
    const float* bm2      = (const float*)d_in[13];

    float* ws = (float*)d_ws;
    size_t off = 0;
    __half* h1 = (__half*)(ws + off); off += 16 * (size_t)N_NODES;
    float* a_src1 = ws + off; off += 2  * (size_t)N_NODES;
    float* a_dst1 = ws + off; off += 2  * (size_t)N_NODES;
    float* out1   = ws + off; off += 32 * (size_t)N_NODES;
    __half* h2 = (__half*)(ws + off); off += 16 * (size_t)N_NODES;  // fp16 now (region kept same size)
    float* a_src2 = ws + off; off += 1  * (size_t)N_NODES;
    float* a_dst2 = ws + off; off += 1  * (size_t)N_NODES;
    float* out2   = ws + off; off += 16 * (size_t)N_NODES;
    __half* u = (__half*)(ws + off); off += 8 * (size_t)N_NODES;
    __half* v = (__half*)(ws + off); off += 8 * (size_t)N_NODES;
    int* cnt     = (int*)(ws + off); off += (size_t)N_NODES * CNT_PAD;
    int* csr_src = (int*)(ws + off); off += (size_t)N_NODES * CAP;
    int* gcnt    = (int*)(ws + off); off += 256;
    int* flag    = (int*)(ws + off); off += 64;
    // bseg (16.06 MB) overlays the h1..out2 region: dead before k1_gemm1 runs.
    int2* bseg = (int2*)ws;

    k0_detect<<<1, 256, 0, stream>>>(ei, flag, gcnt);
    k_part<<<(N_EDGES + PCHUNK - 1) / PCHUNK, 1024, 0, stream>>>(ei, flag, gcnt, bseg);
    k_sub<<<NBK, 1024, 0, stream>>>(gcnt, bseg, cnt, csr_src);

    k1_gemm1<<<(N_NODES + 63) / 64, 256, 0, stream>>>(
        x, W1, att_src1, att_dst1, h1, a_src1, a_dst1);
    k_agg1<<<(N_NODES + 3) / 4, 256, 0, stream>>>(
        cnt, csr_src, a_src1, a_dst1, h1, out1);
    k4_layer2<<<(N_NODES + 15) / 16, 256, 0, stream>>>(
        out1, b1, W2, att_src2, att_dst2, h2, a_src2, a_dst2);
    k_agg2<<<(N_NODES + 3) / 4, 256, 0, stream>>>(
        cnt, csr_src, a_src2, a_dst2, h2, out2);
    k_prep<<<(N_NODES + 15) / 16, 256, 0, stream>>>(
        out2, b2, Wm1, bm1, u, v);
    k7_lite<<<(N_EDGES + 255) / 256, 256, 0, stream>>>(
        ei, flag, u, v, Wm2, bm2, (float*)d_out);
}

// Round 2
// 259.270 us; speedup vs baseline: 1.0016x; 1.0016x over previous
//
#include <hip/hip_runtime.h>
#include <hip/hip_bf16.h>
#include <hip/hip_fp16.h>

#define N_NODES 50000
#define N_EDGES 1600000
#define IN_CH 256
#define NEG_SLOPE 0.2f
#define EPS_F 1e-16f
#define CNT_PAD 16      // one 64B line per counter (agg kernels read cnt[n*16])
#define CAP 128         // bucket capacity per node (Poisson(32): P(>=128) ~ 1e-37)
#define NBK 196         // coarse buckets: dst>>8, 50000/256 -> 0..195
#define CAPB 10240      // coarse bucket capacity (mean 8163, +23 sigma)
#define PCHUNK 3125     // edges per k_part block (512 * 3125 = 1.6M)
#define KTILE 64                 // 17.4KB xs + 32KB w1s -> 3 blocks/CU
#define XS_PITCH (KTILE + 4)

__device__ __forceinline__ float lrelu(float x) {
    return x > 0.f ? x : NEG_SLOPE * x;
}

__device__ __forceinline__ float2 h2f(unsigned int w) {
    __half2 h;
    *reinterpret_cast<unsigned int*>(&h) = w;
    return __half22float2(h);
}

__device__ __forceinline__ unsigned int f2h2(float a, float b) {
    __half2 h = __floats2half2_rn(a, b);
    return *reinterpret_cast<unsigned int*>(&h);
}

// Inline int64-vs-int32 layout detection: for int64 edge_index the high words
// (odd int positions) are all zero (values in [0, 50000)); for int32 they are
// src values, all-zero with P ~ (2e-5)^64. One L2-hot load + ballot per wave.
__device__ __forceinline__ int detect_i64(const int* __restrict__ ei) {
    const int lane = threadIdx.x & 63;
    const unsigned long long b = __ballot(ei[2 * lane + 1] != 0);
    return b == 0ull ? 1 : 0;
}

__device__ __forceinline__ int ld_src(const int* ei, int f, int e) {
    return f ? ei[2 * (size_t)e] : ei[e];
}
__device__ __forceinline__ int ld_dst(const int* ei, int f, int e) {
    return f ? ei[2 * (size_t)N_EDGES + 2 * (size_t)e]
             : ei[(size_t)N_EDGES + e];
}

// -------- Build pass 1: coarse partition by dst>>8 (LDS hist + cursors) --------
__global__ __launch_bounds__(1024) void k_part(const int* __restrict__ ei,
                                               int* __restrict__ gcnt,
                                               int2* __restrict__ bseg)
{
    __shared__ int hist[NBK];
    __shared__ int cur[NBK];
    const int t = threadIdx.x;
    const int f = detect_i64(ei);
    for (int j = t; j < NBK; j += 1024) hist[j] = 0;
    __syncthreads();
    const int e0 = blockIdx.x * PCHUNK;
    const int e1 = min(e0 + PCHUNK, N_EDGES);
    for (int e = e0 + t; e < e1; e += 1024)
        atomicAdd(&hist[ld_dst(ei, f, e) >> 8], 1);
    __syncthreads();
    for (int j = t; j < NBK; j += 1024)
        cur[j] = j * CAPB + atomicAdd(&gcnt[j], hist[j]);
    __syncthreads();
    for (int e = e0 + t; e < e1; e += 1024) {
        const int s = ld_src(ei, f, e);
        const int d = ld_dst(ei, f, e);
        const int bk = d >> 8;
        const int pos = atomicAdd(&cur[bk], 1);
        if (pos - bk * CAPB < CAPB) bseg[pos] = make_int2(s, d);
    }
}

// -------- Build pass 2: per-bucket fine scatter into fixed-stride CSR --------
__global__ __launch_bounds__(1024) void k_sub(const int* __restrict__ gcnt,
                                              const int2* __restrict__ bseg,
                                              int* __restrict__ cnt,
                                              int* __restrict__ csr_src)
{
    __shared__ int cur[256];
    const int b = blockIdx.x;
    const int t = threadIdx.x;
    if (t < 256) cur[t] = 0;
    __syncthreads();
    const int count = min(gcnt[b], CAPB);
    const int2* seg = bseg + (size_t)b * CAPB;
    for (int i = t; i < count; i += 1024) {
        const int2 e = seg[i];
        const int slot = atomicAdd(&cur[e.y & 255], 1);
        if (slot < CAP) csr_src[((size_t)e.y << 7) + slot] = e.x;
    }
    __syncthreads();
    if (t < 256) {
        const int n = b * 256 + t;
        if (n < N_NODES) cnt[(size_t)n * CNT_PAD] = min(cur[t], CAP);
    }
}

// ---------------- Kernel 1: h1 = x @ W1 (fp16 out) ; a_src1/a_dst1 fused ----------------
// Register-blocked 2 rows x 4 cols; KTILE=64 for 3 blocks/CU occupancy.
__global__ __launch_bounds__(256) void k1_gemm1(
    const float* __restrict__ x, const float* __restrict__ W1,
    const float* __restrict__ att_src1, const float* __restrict__ att_dst1,
    __half* __restrict__ h1, float* __restrict__ a_src1, float* __restrict__ a_dst1)
{
    __shared__ float w1s[IN_CH * 32];        // full K, [k][col]  (32 KB)
    __shared__ float xs[64 * XS_PITCH];      // K-tile of 64      (17.4 KB)
    __shared__ float attss[32], attds[32];
    const int t = threadIdx.x;
    for (int i = t; i < IN_CH * 32; i += 256) w1s[i] = W1[i];
    if (t < 32) { attss[t] = att_src1[t]; attds[t] = att_dst1[t]; }
    const int row0 = blockIdx.x * 64;
    const int colq = t & 7, c4 = colq * 4;
    const int rp = t >> 3;
    const int r0 = rp * 2, r1 = r0 + 1;
    float4 a0 = make_float4(0.f, 0.f, 0.f, 0.f);
    float4 a1 = make_float4(0.f, 0.f, 0.f, 0.f);
    for (int kb = 0; kb < IN_CH; kb += KTILE) {
        __syncthreads();
        #pragma unroll
        for (int i = 0; i < 4; ++i) {        // 64 rows x 16 float4
            const int idx = t + 256 * i;
            const int r = idx >> 4, p = idx & 15;
            const int row = row0 + r;
            float4 vv = make_float4(0.f, 0.f, 0.f, 0.f);
            if (row < N_NODES)
                vv = *(const float4*)(x + (size_t)row * IN_CH + kb + p * 4);
            *(float4*)(&xs[r * XS_PITCH + p * 4]) = vv;
        }
        __syncthreads();
        #pragma unroll 8
        for (int kt = 0; kt < KTILE; ++kt) {
            const float xv0 = xs[r0 * XS_PITCH + kt];
            const float xv1 = xs[r1 * XS_PITCH + kt];
            const float4 wv = *(const float4*)(&w1s[(kb + kt) * 32 + c4]);
            a0.x += xv0 * wv.x; a0.y += xv0 * wv.y;
            a0.z += xv0 * wv.z; a0.w += xv0 * wv.w;
            a1.x += xv1 * wv.x; a1.y += xv1 * wv.y;
            a1.z += xv1 * wv.z; a1.w += xv1 * wv.w;
        }
    }
    const int row_a = row0 + r0, row_b = row0 + r1;
    if (row_a < N_NODES) {
        uint2 p; p.x = f2h2(a0.x, a0.y); p.y = f2h2(a0.z, a0.w);
        *(uint2*)(h1 + (size_t)row_a * 32 + c4) = p;
    }
    if (row_b < N_NODES) {
        uint2 p; p.x = f2h2(a1.x, a1.y); p.y = f2h2(a1.z, a1.w);
        *(uint2*)(h1 + (size_t)row_b * 32 + c4) = p;
    }
    float sa0 = a0.x * attss[c4] + a0.y * attss[c4 + 1]
              + a0.z * attss[c4 + 2] + a0.w * attss[c4 + 3];
    float sd0 = a0.x * attds[c4] + a0.y * attds[c4 + 1]
              + a0.z * attds[c4 + 2] + a0.w * attds[c4 + 3];
    float sa1 = a1.x * attss[c4] + a1.y * attss[c4 + 1]
              + a1.z * attss[c4 + 2] + a1.w * attss[c4 + 3];
    float sd1 = a1.x * attds[c4] + a1.y * attds[c4 + 1]
              + a1.z * attds[c4 + 2] + a1.w * attds[c4 + 3];
    sa0 += __shfl_xor(sa0, 1); sa0 += __shfl_xor(sa0, 2);
    sd0 += __shfl_xor(sd0, 1); sd0 += __shfl_xor(sd0, 2);
    sa1 += __shfl_xor(sa1, 1); sa1 += __shfl_xor(sa1, 2);
    sd1 += __shfl_xor(sd1, 1); sd1 += __shfl_xor(sd1, 2);
    const int head = colq >> 2;
    if ((colq & 3) == 0) {
        if (row_a < N_NODES) {
            a_src1[row_a * 2 + head] = sa0;
            a_dst1[row_a * 2 + head] = sd0;
        }
        if (row_b < N_NODES) {
            a_src1[row_b * 2 + head] = sa1;
            a_dst1[row_b * 2 + head] = sd1;
        }
    }
}

// -------- Layer-1 aggregation FUSED with layer-2 transform --------
// Edge loop: half2-packed gathers, 4 edge-slots/wave (unchanged from prev round).
// Epilogue: the wave holds all 32 channels of out1 for its node -> apply
// bias+ELU, 32->16 GEMV with W2, and a_src2/a_dst2 dots in-register/LDS.
// Eliminates the k4_layer2 kernel and the out1 global round-trip.
__global__ __launch_bounds__(256) void k_agg1f(
    const int* __restrict__ cnt, const int* __restrict__ csr_src,
    const float* __restrict__ a_src1, const float* __restrict__ a_dst1,
    const __half* __restrict__ h1,
    const float* __restrict__ b1, const float* __restrict__ W2,
    const float* __restrict__ att_src2, const float* __restrict__ att_dst2,
    __half* __restrict__ h2, float* __restrict__ a_src2, float* __restrict__ a_dst2)
{
    __shared__ float w2s[32 * 16];
    __shared__ float b1s[32], as2[16], ad2[16];
    __shared__ float act_s[4][32];
    const int t = threadIdx.x;
    for (int i = t; i < 512; i += 256) w2s[i] = W2[i];
    if (t < 32) b1s[t] = b1[t];
    if (t < 16) { as2[t] = att_src2[t]; ad2[t] = att_dst2[t]; }

    const int wid = (blockIdx.x * 256 + t) >> 6;       // grid is exactly 50000 waves
    const int lane = t & 63;
    const int wv = t >> 6;
    const int active = (wid < N_NODES);
    const int len = active ? min(cnt[(size_t)wid * CNT_PAD], CAP) : 0;
    const int beg = wid << 7, end = beg + len;
    float2 ad = make_float2(0.f, 0.f);
    if (active) ad = *(const float2*)(a_dst1 + 2 * (size_t)wid);
    const int slot = lane >> 4, chp = lane & 15;
    const int head = chp >> 3;
    const float adh = head ? ad.y : ad.x;
    const int rep = ((chp & 7) == 0);
    const unsigned int* __restrict__ h1u = (const unsigned int*)h1;
    float accx = 0.f, accy = 0.f, sw = 0.f;
    int i = beg + slot;
    for (; i + 28 < end; i += 32) {          // 32 edges / wave-iter
        int s[8]; float a[8]; unsigned int hw[8]; float w[8];
        #pragma unroll
        for (int j = 0; j < 8; ++j) s[j] = csr_src[i + 4 * j];
        #pragma unroll
        for (int j = 0; j < 8; ++j) a[j] = a_src1[2 * (size_t)s[j] + head];
        #pragma unroll
        for (int j = 0; j < 8; ++j) hw[j] = h1u[(size_t)s[j] * 16 + chp];
        #pragma unroll
        for (int j = 0; j < 8; ++j) w[j] = __expf(lrelu(a[j] + adh));
        float wsum = 0.f;
        #pragma unroll
        for (int j = 0; j < 8; ++j) {
            const float2 hf = h2f(hw[j]);
            wsum += w[j];
            accx += w[j] * hf.x; accy += w[j] * hf.y;
        }
        if (rep) sw += wsum;
    }
    for (; i + 12 < end; i += 16) {          // mid tier: 16 edges / wave-iter
        int s[4]; float a[4]; unsigned int hw[4]; float w[4];
        #pragma unroll
        for (int j = 0; j < 4; ++j) s[j] = csr_src[i + 4 * j];
        #pragma unroll
        for (int j = 0; j < 4; ++j) a[j] = a_src1[2 * (size_t)s[j] + head];
        #pragma unroll
        for (int j = 0; j < 4; ++j) hw[j] = h1u[(size_t)s[j] * 16 + chp];
        #pragma unroll
        for (int j = 0; j < 4; ++j) w[j] = __expf(lrelu(a[j] + adh));
        float wsum = 0.f;
        #pragma unroll
        for (int j = 0; j < 4; ++j) {
            const float2 hf = h2f(hw[j]);
            wsum += w[j];
            accx += w[j] * hf.x; accy += w[j] * hf.y;
        }
        if (rep) sw += wsum;
    }
    for (; i < end; i += 4) {
        const int s = csr_src[i];
        const float w = __expf(lrelu(a_src1[2 * (size_t)s + head] + adh));
        if (rep) sw += w;
        const float2 hf = h2f(h1u[(size_t)s * 16 + chp]);
        accx += w * hf.x; accy += w * hf.y;
    }
    // reduce across the 4 slots (lanes differ in bits 4,5)
    sw += __shfl_xor(sw, 16); sw += __shfl_xor(sw, 32);
    const float swh = __shfl(sw, head << 3);
    accx += __shfl_xor(accx, 16); accx += __shfl_xor(accx, 32);
    accy += __shfl_xor(accy, 16); accy += __shfl_xor(accy, 32);
    const float inv = 1.f / (swh + EPS_F);
    // ---- fused layer-2 transform (was k4_layer2) ----
    if (lane < 16) {
        float ax = accx * inv + b1s[2 * chp];
        float ay = accy * inv + b1s[2 * chp + 1];
        ax = ax > 0.f ? ax : expm1f(ax);
        ay = ay > 0.f ? ay : expm1f(ay);
        act_s[wv][2 * chp] = ax;
        act_s[wv][2 * chp + 1] = ay;
    }
    __syncthreads();            // covers w2s/b1s/as2/ad2 loads + act_s writes
    const int j = lane & 15;
    float acc2 = 0.f;
    #pragma unroll
    for (int k = 0; k < 32; ++k) acc2 += act_s[wv][k] * w2s[k * 16 + j];
    if (lane < 16 && active) h2[(size_t)wid * 16 + j] = __float2half(acc2);
    float sa = acc2 * as2[j], sd = acc2 * ad2[j];
    sa += __shfl_xor(sa, 1); sa += __shfl_xor(sa, 2);
    sa += __shfl_xor(sa, 4); sa += __shfl_xor(sa, 8);
    sd += __shfl_xor(sd, 1); sd += __shfl_xor(sd, 2);
    sd += __shfl_xor(sd, 4); sd += __shfl_xor(sd, 8);
    if (lane == 0 && active) { a_src2[wid] = sa; a_dst2[wid] = sd; }
}

// -------- Layer-2 aggregation FUSED with edge-MLP node hoist --------
// Edge loop: half2-packed h2 gathers, 8 edge-slots/wave (unchanged).
// Epilogue: wave holds all 16 channels of out2 -> compute u/v = (out2+b2)@Wm1
// halves directly. Eliminates k_prep and the out2 global round-trip.
__global__ __launch_bounds__(256) void k_agg2f(
    const int* __restrict__ cnt, const int* __restrict__ csr_src,
    const float* __restrict__ a_src2, const float* __restrict__ a_dst2,
    const __half* __restrict__ h2,
    const float* __restrict__ b2, const float* __restrict__ Wm1,
    const float* __restrict__ bm1,
    __half* __restrict__ u, __half* __restrict__ v)
{
    __shared__ float wa[16 * 16], wb[16 * 16];
    __shared__ float b2s[16], bm1s[16];
    __shared__ float act_s[4][16];
    const int t = threadIdx.x;
    if (t < 256) { wa[t] = Wm1[t]; wb[t] = Wm1[256 + t]; }
    if (t < 16) { b2s[t] = b2[t]; bm1s[t] = bm1[t]; }

    const int wid = (blockIdx.x * 256 + t) >> 6;
    const int lane = t & 63;
    const int wv = t >> 6;
    const int active = (wid < N_NODES);
    const int len = active ? min(cnt[(size_t)wid * CNT_PAD], CAP) : 0;
    const int beg = wid << 7, end = beg + len;
    const float ad = active ? a_dst2[wid] : 0.f;
    const int slot = lane >> 3, chp = lane & 7;
    const int rep = (chp == 0);
    const unsigned int* __restrict__ h2u = (const unsigned int*)h2;
    float accx = 0.f, accy = 0.f, sw = 0.f;
    int i = beg + slot;
    for (; i + 24 < end; i += 32) {          // 32 edges / wave-iter
        int s[4]; float a[4]; unsigned int hw[4]; float w[4];
        #pragma unroll
        for (int j = 0; j < 4; ++j) s[j] = csr_src[i + 8 * j];
        #pragma unroll
        for (int j = 0; j < 4; ++j) a[j] = a_src2[s[j]];
        #pragma unroll
        for (int j = 0; j < 4; ++j) hw[j] = h2u[(size_t)s[j] * 8 + chp];
        #pragma unroll
        for (int j = 0; j < 4; ++j) w[j] = __expf(lrelu(a[j] + ad));
        float wsum = 0.f;
        #pragma unroll
        for (int j = 0; j < 4; ++j) {
            const float2 hf = h2f(hw[j]);
            wsum += w[j];
            accx += w[j] * hf.x; accy += w[j] * hf.y;
        }
        if (rep) sw += wsum;
    }
    for (; i < end; i += 8) {
        const int s = csr_src[i];
        const float w = __expf(lrelu(a_src2[s] + ad));
        if (rep) sw += w;
        const float2 hf = h2f(h2u[(size_t)s * 8 + chp]);
        accx += w * hf.x; accy += w * hf.y;
    }
    // reduce across the 8 slots (lanes differ in bits 3,4,5)
    sw += __shfl_xor(sw, 8); sw += __shfl_xor(sw, 16); sw += __shfl_xor(sw, 32);
    const float swt = __shfl(sw, 0);
    accx += __shfl_xor(accx, 8); accx += __shfl_xor(accx, 16); accx += __shfl_xor(accx, 32);
    accy += __shfl_xor(accy, 8); accy += __shfl_xor(accy, 16); accy += __shfl_xor(accy, 32);
    const float inv = 1.f / (swt + EPS_F);
    // ---- fused edge-MLP node hoist (was k_prep) ----
    if (lane < 8) {
        float2 o;
        o.x = accx * inv + b2s[2 * chp];
        o.y = accy * inv + b2s[2 * chp + 1];
        *(float2*)(&act_s[wv][2 * chp]) = o;
    }
    __syncthreads();            // covers wa/wb/b2s/bm1s loads + act_s writes
    const int c = lane & 15;
    float su = bm1s[c], sv = 0.f;
    #pragma unroll
    for (int k = 0; k < 16; ++k) {
        const float a = act_s[wv][k];
        su += a * wa[k * 16 + c];
        sv += a * wb[k * 16 + c];
    }
    if (lane < 16 && active) {
        u[(size_t)wid * 16 + c] = __float2half(su);
        v[(size_t)wid * 16 + c] = __float2half(sv);
    }
}

// ---------------- Kernel 7 lite: per-edge tail of the MLP (fp16 gathers) ----------------
__global__ __launch_bounds__(256) void k7_lite(
    const int* __restrict__ ei,
    const __half* __restrict__ u, const __half* __restrict__ v,
    const float* __restrict__ Wm2, const float* __restrict__ bm2,
    float* __restrict__ out)
{
    __shared__ float wm2s[16];
    __shared__ float bm2s;
    const int t = threadIdx.x;
    const int f = detect_i64(ei);
    if (t < 16) wm2s[t] = Wm2[t];
    if (t == 0) bm2s = bm2[0];
    __syncthreads();
    const int e = blockIdx.x * 256 + t;
    if (e >= N_EDGES) return;
    const int s = ld_src(ei, f, e);
    const int d = ld_dst(ei, f, e);
    const uint4* up = (const uint4*)(u + (size_t)s * 16);
    const uint4* vp = (const uint4*)(v + (size_t)d * 16);
    const uint4 ua = up[0], ub = up[1];
    const uint4 va = vp[0], vb = vp[1];
    float fl = bm2s;
    unsigned int uw[8] = {ua.x, ua.y, ua.z, ua.w, ub.x, ub.y, ub.z, ub.w};
    unsigned int vw[8] = {va.x, va.y, va.z, va.w, vb.x, vb.y, vb.z, vb.w};
    #pragma unroll
    for (int i = 0; i < 8; ++i) {
        const float2 a = h2f(uw[i]);
        const float2 b = h2f(vw[i]);
        fl += fmaxf(a.x + b.x, 0.f) * wm2s[2 * i];
        fl += fmaxf(a.y + b.y, 0.f) * wm2s[2 * i + 1];
    }
    out[e] = fmaxf(fl, 0.f);
}

extern "C" void kernel_launch(void* const* d_in, const int* in_sizes, int n_in,
                              void* d_out, int out_size, void* d_ws, size_t ws_size,
                              hipStream_t stream)
{
    const float* x        = (const float*)d_in[0];
    const int*   ei       = (const int*)d_in[1];
    const float* W1       = (const float*)d_in[2];
    const float* att_src1 = (const float*)d_in[3];
    const float* att_dst1 = (const float*)d_in[4];
    const float* b1       = (const float*)d_in[5];
    const float* W2       = (const float*)d_in[6];
    const float* att_src2 = (const float*)d_in[7];
    const float* att_dst2 = (const float*)d_in[8];
    const float* b2       = (const float*)d_in[9];
    const float* Wm1      = (const float*)d_in[10];
    const float* bm1      = (const float*)d_in[11];
    const float* Wm2      = (const float*)d_in[12];
    const float* bm2      = (const float*)d_in[13];

    float* ws = (float*)d_ws;
    size_t off = 0;
    __half* h1 = (__half*)(ws + off); off += 16 * (size_t)N_NODES;
    float* a_src1 = ws + off; off += 2  * (size_t)N_NODES;
    float* a_dst1 = ws + off; off += 2  * (size_t)N_NODES;
    float* out1_dead = ws + off; off += 32 * (size_t)N_NODES;  // spacer: keeps bseg overlay clear of cnt/csr
    __half* h2 = (__half*)(ws + off); off += 16 * (size_t)N_NODES;
    float* a_src2 = ws + off; off += 1  * (size_t)N_NODES;
    float* a_dst2 = ws + off; off += 1  * (size_t)N_NODES;
    float* out2_dead = ws + off; off += 16 * (size_t)N_NODES;  // spacer
    __half* u = (__half*)(ws + off); off += 8 * (size_t)N_NODES;
    __half* v = (__half*)(ws + off); off += 8 * (size_t)N_NODES;
    int* cnt     = (int*)(ws + off); off += (size_t)N_NODES * CNT_PAD;
    int* csr_src = (int*)(ws + off); off += (size_t)N_NODES * CAP;
    int* gcnt    = (int*)(ws + off); off += 256;
    int* flag    = (int*)(ws + off); off += 64;
    (void)out1_dead; (void)out2_dead; (void)flag;
    // bseg (16.06 MB) overlays the h1..out2 region: dead before k1_gemm1 runs.
    int2* bseg = (int2*)ws;

    hipMemsetAsync(gcnt, 0, 256 * sizeof(int), stream);
    k_part<<<(N_EDGES + PCHUNK - 1) / PCHUNK, 1024, 0, stream>>>(ei, gcnt, bseg);
    k_sub<<<NBK, 1024, 0, stream>>>(gcnt, bseg, cnt, csr_src);

    k1_gemm1<<<(N_NODES + 63) / 64, 256, 0, stream>>>(
        x, W1, att_src1, att_dst1, h1, a_src1, a_dst1);
    k_agg1f<<<(N_NODES + 3) / 4, 256, 0, stream>>>(
        cnt, csr_src, a_src1, a_dst1, h1, b1, W2, att_src2, att_dst2,
        h2, a_src2, a_dst2);
    k_agg2f<<<(N_NODES + 3) / 4, 256, 0, stream>>>(
        cnt, csr_src, a_src2, a_dst2, h2, b2, Wm1, bm1, u, v);
    k7_lite<<<(N_EDGES + 255) / 256, 256, 0, stream>>>(
        ei, u, v, Wm2, bm2, (float*)d_out);
}

// Round 3
// 259.119 us; speedup vs baseline: 1.0022x; 1.0006x over previous
//
#include <hip/hip_runtime.h>
#include <hip/hip_bf16.h>
#include <hip/hip_fp16.h>

#define N_NODES 50000
#define N_EDGES 1600000
#define IN_CH 256
#define NEG_SLOPE 0.2f
#define EPS_F 1e-16f
#define CNT_PAD 16      // one 64B line per counter (agg kernels read cnt[n*16])
#define CAP 128         // bucket capacity per node (Poisson(32): P(>=128) ~ 1e-37)
#define NBK 196         // coarse buckets: dst>>8, 50000/256 -> 0..195
#define CAPB 10240      // coarse bucket capacity (mean 8163, +23 sigma)
#define PCHUNK 3125     // edges per k_part block (1024 threads x <=4 edges)
#define KTILE 64                 // 17.4KB xs + 32KB w1s -> 3 blocks/CU
#define XS_PITCH (KTILE + 4)

__device__ __forceinline__ float lrelu(float x) {
    return x > 0.f ? x : NEG_SLOPE * x;
}

__device__ __forceinline__ float2 h2f(unsigned int w) {
    __half2 h;
    *reinterpret_cast<unsigned int*>(&h) = w;
    return __half22float2(h);
}

__device__ __forceinline__ unsigned int f2h2(float a, float b) {
    __half2 h = __floats2half2_rn(a, b);
    return *reinterpret_cast<unsigned int*>(&h);
}

// Inline int64-vs-int32 layout detection: for int64 edge_index the high words
// (odd int positions) are all zero (values in [0, 50000)); for int32 they are
// src values, all-zero with P ~ (2e-5)^64. One L2-hot load + ballot per wave.
__device__ __forceinline__ int detect_i64(const int* __restrict__ ei) {
    const int lane = threadIdx.x & 63;
    const unsigned long long b = __ballot(ei[2 * lane + 1] != 0);
    return b == 0ull ? 1 : 0;
}

__device__ __forceinline__ int ld_src(const int* ei, int f, int e) {
    return f ? ei[2 * (size_t)e] : ei[e];
}
__device__ __forceinline__ int ld_dst(const int* ei, int f, int e) {
    return f ? ei[2 * (size_t)N_EDGES + 2 * (size_t)e]
             : ei[(size_t)N_EDGES + e];
}

// -------- Build pass 1: coarse partition by dst>>8, edges register-cached --------
__global__ __launch_bounds__(1024) void k_part(const int* __restrict__ ei,
                                               int* __restrict__ gcnt,
                                               int2* __restrict__ bseg)
{
    __shared__ int hist[NBK];
    __shared__ int cur[NBK];
    const int t = threadIdx.x;
    const int f = detect_i64(ei);
    for (int j = t; j < NBK; j += 1024) hist[j] = 0;
    __syncthreads();
    const int e0 = blockIdx.x * PCHUNK;
    const int e1 = min(e0 + PCHUNK, N_EDGES);
    int es[4], ed[4];
    int ne = 0;
    #pragma unroll
    for (int q = 0; q < 4; ++q) {
        const int e = e0 + t + 1024 * q;
        if (e < e1) {
            es[ne] = ld_src(ei, f, e);
            ed[ne] = ld_dst(ei, f, e);
            ++ne;
        }
    }
    for (int q = 0; q < ne; ++q) atomicAdd(&hist[ed[q] >> 8], 1);
    __syncthreads();
    for (int j = t; j < NBK; j += 1024)
        cur[j] = j * CAPB + atomicAdd(&gcnt[j], hist[j]);
    __syncthreads();
    for (int q = 0; q < ne; ++q) {
        const int bk = ed[q] >> 8;
        const int pos = atomicAdd(&cur[bk], 1);
        if (pos - bk * CAPB < CAPB) bseg[pos] = make_int2(es[q], ed[q]);
    }
}

// -------- Build pass 2: per-bucket fine scatter into fixed-stride CSR --------
__global__ __launch_bounds__(1024) void k_sub(const int* __restrict__ gcnt,
                                              const int2* __restrict__ bseg,
                                              int* __restrict__ cnt,
                                              int* __restrict__ csr_src)
{
    __shared__ int cur[256];
    const int b = blockIdx.x;
    const int t = threadIdx.x;
    if (t < 256) cur[t] = 0;
    __syncthreads();
    const int count = min(gcnt[b], CAPB);
    const int2* seg = bseg + (size_t)b * CAPB;
    for (int i = t; i < count; i += 1024) {
        const int2 e = seg[i];
        const int slot = atomicAdd(&cur[e.y & 255], 1);
        if (slot < CAP) csr_src[((size_t)e.y << 7) + slot] = e.x;
    }
    __syncthreads();
    if (t < 256) {
        const int n = b * 256 + t;
        if (n < N_NODES) cnt[(size_t)n * CNT_PAD] = min(cur[t], CAP);
    }
}

// ---------------- Kernel 1: h1 = x @ W1 (fp16 out) ; a_src1/a_dst1 fused ----------------
// Register-blocked 2 rows x 4 cols; KTILE=64 for 3 blocks/CU occupancy.
__global__ __launch_bounds__(256) void k1_gemm1(
    const float* __restrict__ x, const float* __restrict__ W1,
    const float* __restrict__ att_src1, const float* __restrict__ att_dst1,
    __half* __restrict__ h1, float* __restrict__ a_src1, float* __restrict__ a_dst1)
{
    __shared__ float w1s[IN_CH * 32];        // full K, [k][col]  (32 KB)
    __shared__ float xs[64 * XS_PITCH];      // K-tile of 64      (17.4 KB)
    __shared__ float attss[32], attds[32];
    const int t = threadIdx.x;
    for (int i = t; i < IN_CH * 32; i += 256) w1s[i] = W1[i];
    if (t < 32) { attss[t] = att_src1[t]; attds[t] = att_dst1[t]; }
    const int row0 = blockIdx.x * 64;
    const int colq = t & 7, c4 = colq * 4;
    const int rp = t >> 3;
    const int r0 = rp * 2, r1 = r0 + 1;
    float4 a0 = make_float4(0.f, 0.f, 0.f, 0.f);
    float4 a1 = make_float4(0.f, 0.f, 0.f, 0.f);
    for (int kb = 0; kb < IN_CH; kb += KTILE) {
        __syncthreads();
        #pragma unroll
        for (int i = 0; i < 4; ++i) {        // 64 rows x 16 float4
            const int idx = t + 256 * i;
            const int r = idx >> 4, p = idx & 15;
            const int row = row0 + r;
            float4 vv = make_float4(0.f, 0.f, 0.f, 0.f);
            if (row < N_NODES)
                vv = *(const float4*)(x + (size_t)row * IN_CH + kb + p * 4);
            *(float4*)(&xs[r * XS_PITCH + p * 4]) = vv;
        }
        __syncthreads();
        #pragma unroll 8
        for (int kt = 0; kt < KTILE; ++kt) {
            const float xv0 = xs[r0 * XS_PITCH + kt];
            const float xv1 = xs[r1 * XS_PITCH + kt];
            const float4 wv = *(const float4*)(&w1s[(kb + kt) * 32 + c4]);
            a0.x += xv0 * wv.x; a0.y += xv0 * wv.y;
            a0.z += xv0 * wv.z; a0.w += xv0 * wv.w;
            a1.x += xv1 * wv.x; a1.y += xv1 * wv.y;
            a1.z += xv1 * wv.z; a1.w += xv1 * wv.w;
        }
    }
    const int row_a = row0 + r0, row_b = row0 + r1;
    if (row_a < N_NODES) {
        uint2 p; p.x = f2h2(a0.x, a0.y); p.y = f2h2(a0.z, a0.w);
        *(uint2*)(h1 + (size_t)row_a * 32 + c4) = p;
    }
    if (row_b < N_NODES) {
        uint2 p; p.x = f2h2(a1.x, a1.y); p.y = f2h2(a1.z, a1.w);
        *(uint2*)(h1 + (size_t)row_b * 32 + c4) = p;
    }
    float sa0 = a0.x * attss[c4] + a0.y * attss[c4 + 1]
              + a0.z * attss[c4 + 2] + a0.w * attss[c4 + 3];
    float sd0 = a0.x * attds[c4] + a0.y * attds[c4 + 1]
              + a0.z * attds[c4 + 2] + a0.w * attds[c4 + 3];
    float sa1 = a1.x * attss[c4] + a1.y * attss[c4 + 1]
              + a1.z * attss[c4 + 2] + a1.w * attss[c4 + 3];
    float sd1 = a1.x * attds[c4] + a1.y * attds[c4 + 1]
              + a1.z * attds[c4 + 2] + a1.w * attds[c4 + 3];
    sa0 += __shfl_xor(sa0, 1); sa0 += __shfl_xor(sa0, 2);
    sd0 += __shfl_xor(sd0, 1); sd0 += __shfl_xor(sd0, 2);
    sa1 += __shfl_xor(sa1, 1); sa1 += __shfl_xor(sa1, 2);
    sd1 += __shfl_xor(sd1, 1); sd1 += __shfl_xor(sd1, 2);
    const int head = colq >> 2;
    if ((colq & 3) == 0) {
        if (row_a < N_NODES) {
            a_src1[row_a * 2 + head] = sa0;
            a_dst1[row_a * 2 + head] = sd0;
        }
        if (row_b < N_NODES) {
            a_src1[row_b * 2 + head] = sa1;
            a_dst1[row_b * 2 + head] = sd1;
        }
    }
}

// -------- Layer-1 aggregation (lane-cooperative) FUSED with layer-2 transform --------
// Phase A: lane -> (edge = lane>>1, head = lane&1); one csr load, one logit load,
// ONE expf per lane covers 32 edges x 2 heads per iteration (was 8 expf/lane).
// Phase B: channel lanes (slot = lane>>4, chp = lane&15) pull (s, w) via __shfl
// and do only the h1 gather + FMA. Predication replaces the 3-tier tail loops.
__global__ __launch_bounds__(256) void k_agg1f(
    const int* __restrict__ cnt, const int* __restrict__ csr_src,
    const float* __restrict__ a_src1, const float* __restrict__ a_dst1,
    const __half* __restrict__ h1,
    const float* __restrict__ b1, const float* __restrict__ W2,
    const float* __restrict__ att_src2, const float* __restrict__ att_dst2,
    __half* __restrict__ h2, float* __restrict__ a_src2, float* __restrict__ a_dst2)
{
    __shared__ float w2s[32 * 16];
    __shared__ float b1s[32], as2[16], ad2[16];
    __shared__ float act_s[4][32];
    const int t = threadIdx.x;
    for (int i = t; i < 512; i += 256) w2s[i] = W2[i];
    if (t < 32) b1s[t] = b1[t];
    if (t < 16) { as2[t] = att_src2[t]; ad2[t] = att_dst2[t]; }

    const int wid = (blockIdx.x * 256 + t) >> 6;       // grid is exactly 50000 waves
    const int lane = t & 63;
    const int wv = t >> 6;
    const int active = (wid < N_NODES);
    const int len = active ? min(cnt[(size_t)wid * CNT_PAD], CAP) : 0;
    const int beg = wid << 7, end = beg + len;
    float2 ad = make_float2(0.f, 0.f);
    if (active) ad = *(const float2*)(a_dst1 + 2 * (size_t)wid);

    const int e_off = lane >> 1;          // phase-A edge within 32-block
    const int hh = lane & 1;              // phase-A head
    const float adh_a = hh ? ad.y : ad.x;
    const int slot = lane >> 4, chp = lane & 15;   // phase-B mapping
    const int head = chp >> 3;

    const unsigned int* __restrict__ h1u = (const unsigned int*)h1;
    float accx = 0.f, accy = 0.f, sw = 0.f;
    for (int i0 = beg; i0 < end; i0 += 32) {
        const int el = i0 + e_off;
        int s_a = 0; float w_a = 0.f;
        if (el < end) {
            s_a = csr_src[el];
            const float av = a_src1[2 * (size_t)s_a + hh];
            w_a = __expf(lrelu(av + adh_a));
        }
        sw += w_a;
        #pragma unroll
        for (int j = 0; j < 8; ++j) {
            const int sl = (slot * 8 + j) * 2;
            const int s_j = __shfl(s_a, sl);
            const float w_j = __shfl(w_a, sl + head);
            const float2 hf = h2f(h1u[(size_t)s_j * 16 + chp]);
            accx += w_j * hf.x; accy += w_j * hf.y;
        }
    }
    // sw: lanes of equal parity hold disjoint edges of the same head class
    sw += __shfl_xor(sw, 2); sw += __shfl_xor(sw, 4);
    sw += __shfl_xor(sw, 8); sw += __shfl_xor(sw, 16); sw += __shfl_xor(sw, 32);
    const float swh = __shfl(sw, head);   // lane0 = head0 sum, lane1 = head1 sum
    accx += __shfl_xor(accx, 16); accx += __shfl_xor(accx, 32);
    accy += __shfl_xor(accy, 16); accy += __shfl_xor(accy, 32);
    const float inv = 1.f / (swh + EPS_F);
    // ---- fused layer-2 transform (was k4_layer2) ----
    if (lane < 16) {
        float ax = accx * inv + b1s[2 * chp];
        float ay = accy * inv + b1s[2 * chp + 1];
        ax = ax > 0.f ? ax : expm1f(ax);
        ay = ay > 0.f ? ay : expm1f(ay);
        act_s[wv][2 * chp] = ax;
        act_s[wv][2 * chp + 1] = ay;
    }
    __syncthreads();            // covers w2s/b1s/as2/ad2 loads + act_s writes
    const int j = lane & 15;
    float acc2 = 0.f;
    #pragma unroll
    for (int k = 0; k < 32; ++k) acc2 += act_s[wv][k] * w2s[k * 16 + j];
    if (lane < 16 && active) h2[(size_t)wid * 16 + j] = __float2half(acc2);
    float sa = acc2 * as2[j], sd = acc2 * ad2[j];
    sa += __shfl_xor(sa, 1); sa += __shfl_xor(sa, 2);
    sa += __shfl_xor(sa, 4); sa += __shfl_xor(sa, 8);
    sd += __shfl_xor(sd, 1); sd += __shfl_xor(sd, 2);
    sd += __shfl_xor(sd, 4); sd += __shfl_xor(sd, 8);
    if (lane == 0 && active) { a_src2[wid] = sa; a_dst2[wid] = sd; }
}

// -------- Layer-2 aggregation (lane-cooperative, 64 edges/iter) + edge-MLP hoist --------
// Phase A: lane -> edge (64 edges per iteration; one iteration for nearly all
// nodes at Poisson(32)). Phase B: slot = lane>>3, chp = lane&7.
__global__ __launch_bounds__(256) void k_agg2f(
    const int* __restrict__ cnt, const int* __restrict__ csr_src,
    const float* __restrict__ a_src2, const float* __restrict__ a_dst2,
    const __half* __restrict__ h2,
    const float* __restrict__ b2, const float* __restrict__ Wm1,
    const float* __restrict__ bm1,
    __half* __restrict__ u, __half* __restrict__ v)
{
    __shared__ float wa[16 * 16], wb[16 * 16];
    __shared__ float b2s[16], bm1s[16];
    __shared__ float act_s[4][16];
    const int t = threadIdx.x;
    if (t < 256) { wa[t] = Wm1[t]; wb[t] = Wm1[256 + t]; }
    if (t < 16) { b2s[t] = b2[t]; bm1s[t] = bm1[t]; }

    const int wid = (blockIdx.x * 256 + t) >> 6;
    const int lane = t & 63;
    const int wv = t >> 6;
    const int active = (wid < N_NODES);
    const int len = active ? min(cnt[(size_t)wid * CNT_PAD], CAP) : 0;
    const int beg = wid << 7, end = beg + len;
    const float ad = active ? a_dst2[wid] : 0.f;
    const int slot = lane >> 3, chp = lane & 7;
    const unsigned int* __restrict__ h2u = (const unsigned int*)h2;
    float accx = 0.f, accy = 0.f, sw = 0.f;
    for (int i0 = beg; i0 < end; i0 += 64) {
        const int el = i0 + lane;
        int s_a = 0; float w_a = 0.f;
        if (el < end) {
            s_a = csr_src[el];
            w_a = __expf(lrelu(a_src2[s_a] + ad));
        }
        sw += w_a;
        #pragma unroll
        for (int j = 0; j < 8; ++j) {
            const int sl = slot * 8 + j;
            const int s_j = __shfl(s_a, sl);
            const float w_j = __shfl(w_a, sl);
            const float2 hf = h2f(h2u[(size_t)s_j * 8 + chp]);
            accx += w_j * hf.x; accy += w_j * hf.y;
        }
    }
    sw += __shfl_xor(sw, 1); sw += __shfl_xor(sw, 2); sw += __shfl_xor(sw, 4);
    sw += __shfl_xor(sw, 8); sw += __shfl_xor(sw, 16); sw += __shfl_xor(sw, 32);
    accx += __shfl_xor(accx, 8); accx += __shfl_xor(accx, 16); accx += __shfl_xor(accx, 32);
    accy += __shfl_xor(accy, 8); accy += __shfl_xor(accy, 16); accy += __shfl_xor(accy, 32);
    const float inv = 1.f / (sw + EPS_F);
    // ---- fused edge-MLP node hoist (was k_prep) ----
    if (lane < 8) {
        float2 o;
        o.x = accx * inv + b2s[2 * chp];
        o.y = accy * inv + b2s[2 * chp + 1];
        *(float2*)(&act_s[wv][2 * chp]) = o;
    }
    __syncthreads();            // covers wa/wb/b2s/bm1s loads + act_s writes
    const int c = lane & 15;
    float su = bm1s[c], sv = 0.f;
    #pragma unroll
    for (int k = 0; k < 16; ++k) {
        const float a = act_s[wv][k];
        su += a * wa[k * 16 + c];
        sv += a * wb[k * 16 + c];
    }
    if (lane < 16 && active) {
        u[(size_t)wid * 16 + c] = __float2half(su);
        v[(size_t)wid * 16 + c] = __float2half(sv);
    }
}

// ---------------- Kernel 7 lite: per-edge tail of the MLP (fp16 gathers) ----------------
__global__ __launch_bounds__(256) void k7_lite(
    const int* __restrict__ ei,
    const __half* __restrict__ u, const __half* __restrict__ v,
    const float* __restrict__ Wm2, const float* __restrict__ bm2,
    float* __restrict__ out)
{
    __shared__ float wm2s[16];
    __shared__ float bm2s;
    const int t = threadIdx.x;
    const int f = detect_i64(ei);
    if (t < 16) wm2s[t] = Wm2[t];
    if (t == 0) bm2s = bm2[0];
    __syncthreads();
    const int e = blockIdx.x * 256 + t;
    if (e >= N_EDGES) return;
    const int s = ld_src(ei, f, e);
    const int d = ld_dst(ei, f, e);
    const uint4* up = (const uint4*)(u + (size_t)s * 16);
    const uint4* vp = (const uint4*)(v + (size_t)d * 16);
    const uint4 ua = up[0], ub = up[1];
    const uint4 va = vp[0], vb = vp[1];
    float fl = bm2s;
    unsigned int uw[8] = {ua.x, ua.y, ua.z, ua.w, ub.x, ub.y, ub.z, ub.w};
    unsigned int vw[8] = {va.x, va.y, va.z, va.w, vb.x, vb.y, vb.z, vb.w};
    #pragma unroll
    for (int i = 0; i < 8; ++i) {
        const float2 a = h2f(uw[i]);
        const float2 b = h2f(vw[i]);
        fl += fmaxf(a.x + b.x, 0.f) * wm2s[2 * i];
        fl += fmaxf(a.y + b.y, 0.f) * wm2s[2 * i + 1];
    }
    out[e] = fmaxf(fl, 0.f);
}

extern "C" void kernel_launch(void* const* d_in, const int* in_sizes, int n_in,
                              void* d_out, int out_size, void* d_ws, size_t ws_size,
                              hipStream_t stream)
{
    const float* x        = (const float*)d_in[0];
    const int*   ei       = (const int*)d_in[1];
    const float* W1       = (const float*)d_in[2];
    const float* att_src1 = (const float*)d_in[3];
    const float* att_dst1 = (const float*)d_in[4];
    const float* b1       = (const float*)d_in[5];
    const float* W2       = (const float*)d_in[6];
    const float* att_src2 = (const float*)d_in[7];
    const float* att_dst2 = (const float*)d_in[8];
    const float* b2       = (const float*)d_in[9];
    const float* Wm1      = (const float*)d_in[10];
    const float* bm1      = (const float*)d_in[11];
    const float* Wm2      = (const float*)d_in[12];
    const float* bm2      = (const float*)d_in[13];

    float* ws = (float*)d_ws;
    size_t off = 0;
    __half* h1 = (__half*)(ws + off); off += 16 * (size_t)N_NODES;
    float* a_src1 = ws + off; off += 2  * (size_t)N_NODES;
    float* a_dst1 = ws + off; off += 2  * (size_t)N_NODES;
    float* out1_dead = ws + off; off += 32 * (size_t)N_NODES;  // spacer: keeps bseg overlay clear of cnt/csr
    __half* h2 = (__half*)(ws + off); off += 16 * (size_t)N_NODES;
    float* a_src2 = ws + off; off += 1  * (size_t)N_NODES;
    float* a_dst2 = ws + off; off += 1  * (size_t)N_NODES;
    float* out2_dead = ws + off; off += 16 * (size_t)N_NODES;  // spacer
    __half* u = (__half*)(ws + off); off += 8 * (size_t)N_NODES;
    __half* v = (__half*)(ws + off); off += 8 * (size_t)N_NODES;
    int* cnt     = (int*)(ws + off); off += (size_t)N_NODES * CNT_PAD;
    int* csr_src = (int*)(ws + off); off += (size_t)N_NODES * CAP;
    int* gcnt    = (int*)(ws + off); off += 256;
    int* flag    = (int*)(ws + off); off += 64;
    (void)out1_dead; (void)out2_dead; (void)flag;
    // bseg (16.06 MB) overlays the h1..out2 region: dead before k1_gemm1 runs.
    int2* bseg = (int2*)ws;

    hipMemsetAsync(gcnt, 0, 256 * sizeof(int), stream);
    k_part<<<(N_EDGES + PCHUNK - 1) / PCHUNK, 1024, 0, stream>>>(ei, gcnt, bseg);
    k_sub<<<NBK, 1024, 0, stream>>>(gcnt, bseg, cnt, csr_src);

    k1_gemm1<<<(N_NODES + 63) / 64, 256, 0, stream>>>(
        x, W1, att_src1, att_dst1, h1, a_src1, a_dst1);
    k_agg1f<<<(N_NODES + 3) / 4, 256, 0, stream>>>(
        cnt, csr_src, a_src1, a_dst1, h1, b1, W2, att_src2, att_dst2,
        h2, a_src2, a_dst2);
    k_agg2f<<<(N_NODES + 3) / 4, 256, 0, stream>>>(
        cnt, csr_src, a_src2, a_dst2, h2, b2, Wm1, bm1, u, v);
    k7_lite<<<(N_EDGES + 255) / 256, 256, 0, stream>>>(
        ei, u, v, Wm2, bm2, (float*)d_out);
}